// Round 10
// baseline (98.293 us; speedup 1.0000x reference)
//
#include <hip/hip_runtime.h>

#define C_EMB 256
#define NPL   9             // points per level
#define NLV   2             // levels
#define NPTS  (NPL * NLV)   // 18
#define NJ    (NPTS * 2)    // 36 offset outputs per query

__global__ void transpose_woff(const float* __restrict__ W_off, float* __restrict__ WT) {
    // W_off: [C_EMB, NJ] -> WT: [NJ, C_EMB]
    int j = blockIdx.x;       // 0..35
    int c = threadIdx.x;      // 0..255
    WT[j * C_EMB + c] = W_off[c * NJ + j];
}

__device__ __forceinline__ int imin(int a, int b) { return a < b ? a : b; }
__device__ __forceinline__ int imax(int a, int b) { return a > b ? a : b; }

// x + dpp_select(x); shifted-in-from-outside-row lanes contribute 0 (old=0, bound_ctrl=1)
template<int CTRL, int ROW_MASK>
__device__ __forceinline__ float dpp_add(float x) {
    int t = __builtin_amdgcn_update_dpp(0, __builtin_bit_cast(int, x),
                                        CTRL, ROW_MASK, 0xf, true);
    return x + __builtin_bit_cast(float, t);
}

// 32-lane sum with broadcast to all 32 lanes, each wave-half independent.
// Steps: row_shr 1/2/4/8 (cumsum within 16-rows; lane15/31 hold row sums),
// ds_swizzle lane^16 + add (lane15 & lane31 now hold the full 32-sum),
// ds_swizzle lane->(lane&0x10)|0xF (every lane reads its row's lane15/31).
// ds_swizzle BitMode operates independently per 32-lane group on wave64.
__device__ __forceinline__ float half_sum_all(float x) {
    x = dpp_add<0x111, 0xf>(x);   // row_shr:1
    x = dpp_add<0x112, 0xf>(x);   // row_shr:2
    x = dpp_add<0x114, 0xf>(x);   // row_shr:4
    x = dpp_add<0x118, 0xf>(x);   // row_shr:8
    int t = __builtin_amdgcn_ds_swizzle(__builtin_bit_cast(int, x), 0x401F); // lane ^ 16
    x = x + __builtin_bit_cast(float, t);
    int r = __builtin_amdgcn_ds_swizzle(__builtin_bit_cast(int, x), 0x01F0); // (lane&0x10)|0xF
    return __builtin_bit_cast(float, r);
}

// Fused kernel, CHANNEL-SPLIT: one wave = 2 queries; lanes 0-31 own query A,
// lanes 32-63 own query B, 8 channels per lane. Every cross-lane/uniform
// instruction (offsets loop, reductions, geometry, online-softmax update)
// serves two queries -> per-query VALU nearly halves, wave count halves.
template<bool USE_WT>
__global__ __launch_bounds__(128)
void deform_attn_kernel(const float* __restrict__ query,
                        const float* __restrict__ value,
                        const float* __restrict__ refp,
                        const int*   __restrict__ sshapes,
                        const float* __restrict__ WT,
                        const float* __restrict__ W_off,
                        const float* __restrict__ b_off,
                        float*       __restrict__ out,
                        int nq, int nv) {
    const int lane = threadIdx.x & 63;
    const int widx = threadIdx.x >> 6;   // wave within block: 0..1
    const int half = lane >> 5;          // which query this lane serves
    const int hl   = lane & 31;          // lane within the half
    int q = blockIdx.x * 4 + widx * 2 + half;
    if (q >= nq) q = nq - 1;             // clamped tail: duplicate compute, same-value writes

    __shared__ int4   s_idx[2][2][NPTS];
    __shared__ float4 s_w[2][2][NPTS];

    const unsigned cb = (unsigned)hl * 32u;   // byte offset of this lane's 8 channels
    const char* qb = (const char*)query + (size_t)q * (C_EMB * 4);
    float4 qa = *reinterpret_cast<const float4*>(qb + cb);
    float4 qc = *reinterpret_cast<const float4*>(qb + cb + 16);

    // ---------------- sampling offsets: off[j] = dot(q, W_off[:,j]) (+ b_off later) ----------
    float ox = 0.f, oy = 0.f;
    const char* wtb = (const char*)WT;
    #pragma unroll
    for (int j = 0; j < NJ; ++j) {
        float s;
        if (USE_WT) {
            float4 wa = *reinterpret_cast<const float4*>(wtb + (unsigned)(j * 1024) + cb);
            float4 wc = *reinterpret_cast<const float4*>(wtb + (unsigned)(j * 1024) + cb + 16);
            s = qa.x * wa.x + qa.y * wa.y + qa.z * wa.z + qa.w * wa.w
              + qc.x * wc.x + qc.y * wc.y + qc.z * wc.z + qc.w * wc.w;
        } else {
            const float* wp = W_off + (size_t)(hl * 8) * NJ + j;
            s = qa.x * wp[0 * NJ] + qa.y * wp[1 * NJ] + qa.z * wp[2 * NJ] + qa.w * wp[3 * NJ]
              + qc.x * wp[4 * NJ] + qc.y * wp[5 * NJ] + qc.z * wp[6 * NJ] + qc.w * wp[7 * NJ];
        }
        s = half_sum_all(s);             // all 32 lanes of each half get their query's off[j]
        if (j == 2 * hl)     ox = s;
        if (j == 2 * hl + 1) oy = s;
    }

    // ---------------- geometry: hl 0..17 of EACH half handles one (level, point) ------------
    if (hl < NPTS) {
        int p = hl;
        int l = p / NPL;
        int Hi = sshapes[l * 2 + 0];
        int Wi = sshapes[l * 2 + 1];
        float fw = (float)Wi, fh = (float)Hi;
        float rx = refp[((size_t)q * NLV + l) * 2 + 0];
        float ry = refp[((size_t)q * NLV + l) * 2 + 1];
        float2 b2 = *reinterpret_cast<const float2*>(b_off + 2 * p);
        // x = loc*W - 0.5 ; loc = ref + off/W  ->  x = ref*W + off - 0.5
        float x = rx * fw + ox + b2.x - 0.5f;
        float y = ry * fh + oy + b2.y - 0.5f;
        float x0f = floorf(x), y0f = floorf(y);
        int x0 = (int)x0f, y0 = (int)y0f;
        float wx1 = x - x0f, wy1 = y - y0f;
        float wx0 = 1.f - wx1, wy0 = 1.f - wy1;
        bool vx0 = (x0 >= 0) && (x0 <= Wi - 1);
        bool vx1 = (x0 + 1 >= 0) && (x0 + 1 <= Wi - 1);
        bool vy0 = (y0 >= 0) && (y0 <= Hi - 1);
        bool vy1 = (y0 + 1 >= 0) && (y0 + 1 <= Hi - 1);
        int cx0 = imin(imax(x0, 0), Wi - 1);
        int cx1 = imin(imax(x0 + 1, 0), Wi - 1);
        int cy0 = imin(imax(y0, 0), Hi - 1);
        int cy1 = imin(imax(y0 + 1, 0), Hi - 1);
        int base = l * nv;
        int4 id;
        id.x = base + cy0 * Wi + cx0;
        id.y = base + cy0 * Wi + cx1;
        id.z = base + cy1 * Wi + cx0;
        id.w = base + cy1 * Wi + cx1;
        float4 w;
        w.x = wx0 * wy0 * ((vx0 && vy0) ? 1.f : 0.f);
        w.y = wx1 * wy0 * ((vx1 && vy0) ? 1.f : 0.f);
        w.z = wx0 * wy1 * ((vx0 && vy1) ? 1.f : 0.f);
        w.w = wx1 * wy1 * ((vx1 && vy1) ? 1.f : 0.f);
        s_idx[widx][half][p] = id;
        s_w[widx][half][p]   = w;
    }
    __builtin_amdgcn_wave_barrier();   // wave-local LDS producer->consumer; ds ops are wave-ordered

    // scale q once for logits (kv stays unscaled)
    qa.x *= 16.0f; qa.y *= 16.0f; qa.z *= 16.0f; qa.w *= 16.0f;
    qc.x *= 16.0f; qc.y *= 16.0f; qc.z *= 16.0f; qc.w *= 16.0f;

    // ---------------- online-softmax gather loop (both halves in lockstep) -------------------
    const char* vb = (const char*)value;
    float m = -3.0e38f, ssum = 0.f;
    float4 oa; oa.x = 0.f; oa.y = 0.f; oa.z = 0.f; oa.w = 0.f;
    float4 oc; oc.x = 0.f; oc.y = 0.f; oc.z = 0.f; oc.w = 0.f;
    #pragma unroll
    for (int p = 0; p < NPTS; ++p) {
        int4   id = s_idx[widx][half][p];
        float4 w  = s_w[widx][half][p];
        const char* ra = vb + (((unsigned)id.x << 10) + cb);
        const char* rb = vb + (((unsigned)id.y << 10) + cb);
        const char* rc = vb + (((unsigned)id.z << 10) + cb);
        const char* rd = vb + (((unsigned)id.w << 10) + cb);
        const float4 a0 = *reinterpret_cast<const float4*>(ra);
        const float4 a1 = *reinterpret_cast<const float4*>(ra + 16);
        const float4 b0 = *reinterpret_cast<const float4*>(rb);
        const float4 b1 = *reinterpret_cast<const float4*>(rb + 16);
        const float4 c0 = *reinterpret_cast<const float4*>(rc);
        const float4 c1 = *reinterpret_cast<const float4*>(rc + 16);
        const float4 d0 = *reinterpret_cast<const float4*>(rd);
        const float4 d1 = *reinterpret_cast<const float4*>(rd + 16);
        float4 ka, kc;
        ka.x = w.x * a0.x + w.y * b0.x + w.z * c0.x + w.w * d0.x;
        ka.y = w.x * a0.y + w.y * b0.y + w.z * c0.y + w.w * d0.y;
        ka.z = w.x * a0.z + w.y * b0.z + w.z * c0.z + w.w * d0.z;
        ka.w = w.x * a0.w + w.y * b0.w + w.z * c0.w + w.w * d0.w;
        kc.x = w.x * a1.x + w.y * b1.x + w.z * c1.x + w.w * d1.x;
        kc.y = w.x * a1.y + w.y * b1.y + w.z * c1.y + w.w * d1.y;
        kc.z = w.x * a1.z + w.y * b1.z + w.z * c1.z + w.w * d1.z;
        kc.w = w.x * a1.w + w.y * b1.w + w.z * c1.w + w.w * d1.w;
        float dp = qa.x * ka.x + qa.y * ka.y + qa.z * ka.z + qa.w * ka.w
                 + qc.x * kc.x + qc.y * kc.y + qc.z * kc.z + qc.w * kc.w;
        float lg = half_sum_all(dp);       // per-half logit (q pre-scaled by 16)
        float mn = fmaxf(m, lg);
        float sc = __expf(m - mn);         // first iter: underflows to 0
        float pv = __expf(lg - mn);
        ssum = ssum * sc + pv;
        oa.x = oa.x * sc + pv * ka.x;
        oa.y = oa.y * sc + pv * ka.y;
        oa.z = oa.z * sc + pv * ka.z;
        oa.w = oa.w * sc + pv * ka.w;
        oc.x = oc.x * sc + pv * kc.x;
        oc.y = oc.y * sc + pv * kc.y;
        oc.z = oc.z * sc + pv * kc.z;
        oc.w = oc.w * sc + pv * kc.w;
        m = mn;
    }
    float inv = 1.0f / ssum;
    oa.x *= inv; oa.y *= inv; oa.z *= inv; oa.w *= inv;
    oc.x *= inv; oc.y *= inv; oc.z *= inv; oc.w *= inv;
    char* ob = (char*)out + (size_t)q * (C_EMB * 4);
    *reinterpret_cast<float4*>(ob + cb)      = oa;
    *reinterpret_cast<float4*>(ob + cb + 16) = oc;
}

extern "C" void kernel_launch(void* const* d_in, const int* in_sizes, int n_in,
                              void* d_out, int out_size, void* d_ws, size_t ws_size,
                              hipStream_t stream) {
    const float* query = (const float*)d_in[0];
    // d_in[1] = key (unused by forward)
    const float* value = (const float*)d_in[2];
    const float* refp  = (const float*)d_in[3];
    const int*   ss    = (const int*)d_in[4];
    const float* W_off = (const float*)d_in[5];
    const float* b_off = (const float*)d_in[6];
    float* out = (float*)d_out;

    const int nq = in_sizes[0] / C_EMB;          // 20000
    const int nl = in_sizes[4] / 2;              // 2
    const int nv = in_sizes[2] / (nl * C_EMB);   // 16384

    const int blocks = (nq + 3) / 4;             // 4 queries per block (2 waves x 2 halves)

    const size_t wt_bytes = (size_t)NJ * C_EMB * sizeof(float);
    if (ws_size >= wt_bytes) {
        float* WT = (float*)d_ws;
        transpose_woff<<<NJ, C_EMB, 0, stream>>>(W_off, WT);
        deform_attn_kernel<true><<<blocks, 128, 0, stream>>>(
            query, value, refp, ss, WT, W_off, b_off, out, nq, nv);
    } else {
        deform_attn_kernel<false><<<blocks, 128, 0, stream>>>(
            query, value, refp, ss, nullptr, W_off, b_off, out, nq, nv);
    }
}